// Round 1
// baseline (1338.545 us; speedup 1.0000x reference)
//
#include <hip/hip_runtime.h>

#define NCH 24
#define PCH 72
#define HID 64
#define HW 128
#define IMG (HW*HW)            // 16384
#define CHIMG (NCH*IMG)        // per-batch state elems
#define TILE 16
#define TP 18                  // tile + halo
#define TP2 (TP*TP)            // 324

__global__ __launch_bounds__(256) void nca_step_kernel(
    const float* __restrict__ sin, float* __restrict__ sout,
    const float* __restrict__ w1, const float* __restrict__ b1,
    const float* __restrict__ w2, const float* __restrict__ b2,
    const float* __restrict__ mask /* (B,1,128,128) for this step */)
{
    __shared__ float tile[NCH][TP2];   // [c][(y+1)*18 + (x+1)]

    const int b  = blockIdx.z;
    const int y0 = blockIdx.y * TILE;
    const int x0 = blockIdx.x * TILE;
    const int tx = threadIdx.x, ty = threadIdx.y;
    const int tid = ty * TILE + tx;

    const float* sb = sin + b * CHIMG;

    // cooperative halo load (zero pad outside image — conv "SAME")
    for (int idx = tid; idx < NCH * TP2; idx += 256) {
        int c  = idx / TP2;
        int r  = idx - c * TP2;
        int yy = r / TP;
        int xx = r - yy * TP;
        int gy = y0 + yy - 1;
        int gx = x0 + xx - 1;
        float v = 0.0f;
        if ((unsigned)gy < (unsigned)HW && (unsigned)gx < (unsigned)HW)
            v = sb[c * IMG + gy * HW + gx];
        tile[c][r] = v;
    }
    __syncthreads();

    // perception: ident / sobel-x / sobel-y (cross-correlation, /8)
    float p[PCH];
    const int base = (ty + 1) * TP + (tx + 1);
    #pragma unroll
    for (int c = 0; c < NCH; ++c) {
        float tl = tile[c][base - TP - 1], tc_ = tile[c][base - TP], tr = tile[c][base - TP + 1];
        float ml = tile[c][base - 1],      mc  = tile[c][base],      mr = tile[c][base + 1];
        float bl = tile[c][base + TP - 1], bc  = tile[c][base + TP], br = tile[c][base + TP + 1];
        p[3*c + 0] = mc;
        p[3*c + 1] = (-tl + tr - 2.0f*ml + 2.0f*mr - bl + br) * 0.125f;
        p[3*c + 2] = (-tl - 2.0f*tc_ - tr + bl + 2.0f*bc + br) * 0.125f;
    }

    float delta[NCH];
    #pragma unroll
    for (int k = 0; k < NCH; ++k) delta[k] = b2[k];

    // MLP: h = relu(w1 @ p + b1); delta += w2 @ h
    for (int o = 0; o < HID; ++o) {
        const float* wr = w1 + o * PCH;
        float a0 = 0.f, a1 = 0.f, a2 = 0.f, a3 = 0.f;
        #pragma unroll
        for (int c4 = 0; c4 < PCH; c4 += 4) {
            a0 += p[c4 + 0] * wr[c4 + 0];
            a1 += p[c4 + 1] * wr[c4 + 1];
            a2 += p[c4 + 2] * wr[c4 + 2];
            a3 += p[c4 + 3] * wr[c4 + 3];
        }
        float h = b1[o] + ((a0 + a1) + (a2 + a3));
        h = fmaxf(h, 0.0f);
        #pragma unroll
        for (int k = 0; k < NCH; ++k)
            delta[k] += h * w2[k * HID + o];
    }

    const float m = mask[b * IMG + (y0 + ty) * HW + (x0 + tx)];
    const float fire = (m < 0.5f) ? 1.0f : 0.0f;

    const int pix = (y0 + ty) * HW + (x0 + tx);
    #pragma unroll
    for (int k = 0; k < NCH; ++k)
        sout[b * CHIMG + k * IMG + pix] = tile[k][base] + delta[k] * fire;
}

extern "C" void kernel_launch(void* const* d_in, const int* in_sizes, int n_in,
                              void* d_out, int out_size, void* d_ws, size_t ws_size,
                              hipStream_t stream) {
    const float* state = (const float*)d_in[0];
    const float* w1    = (const float*)d_in[1];
    const float* b1    = (const float*)d_in[2];
    const float* w2    = (const float*)d_in[3];
    const float* b2    = (const float*)d_in[4];
    const float* masks = (const float*)d_in[5];

    float* out = (float*)d_out;
    float* ws  = (float*)d_ws;

    dim3 grid(HW / TILE, HW / TILE, 4);
    dim3 block(TILE, TILE, 1);

    for (int step = 0; step < 32; ++step) {
        const float* src = (step == 0) ? state : ((step % 2 == 1) ? ws : out);
        float*       dst = (step % 2 == 0) ? ws : out;
        const float* mstep = masks + (size_t)step * 4 * IMG;
        nca_step_kernel<<<grid, block, 0, stream>>>(src, dst, w1, b1, w2, b2, mstep);
    }
}

// Round 2
// 519.549 us; speedup vs baseline: 2.5764x; 2.5764x over previous
//
#include <hip/hip_runtime.h>

typedef __bf16 bf16x8 __attribute__((ext_vector_type(8)));
typedef float  f32x4  __attribute__((ext_vector_type(4)));

#define NCH 24
#define HW 128
#define IMG (HW*HW)
#define CHIMG (NCH*IMG)
#define TX 16
#define TY 4

// Per-step NCA kernel, MFMA formulation.
//   GEMM1: H^T[h][px]  = sum_k' w1'[h][k'] * ptile[px][k']   (K'=96 = 24ch*4, t=3 slot carries bias-1 trick)
//   GEMM2: dT[o][px]   = sum_h  w2[o][h]   * relu(H)[px][h]  (K=64, M=24 padded to 32)
// mfma_f32_16x16x32_bf16 lane maps: A[row=l%16][k=8*(l/16)+j], B[k=8*(l/16)+j][col=l%16],
// D[row=4*(l/16)+r][col=l%16]  (C/D verified per guide §3).
__global__ __launch_bounds__(256, 4) void nca_step_mfma(
    const float* __restrict__ sin, float* __restrict__ sout,
    const float* __restrict__ w1, const float* __restrict__ b1,
    const float* __restrict__ w2, const float* __restrict__ b2,
    const float* __restrict__ mask)
{
    __shared__ __align__(16) float st[NCH][6][18];    // state tile + halo
    __shared__ __align__(16) short w1f[12*64*8];      // [m][s][lane][j] bf16 bits
    __shared__ __align__(16) short w2f[4*64*8];       // [m2][s2][lane][j]
    __shared__ __align__(16) float b2f[2*64*4];       // [m2][lane][r]
    __shared__ __align__(16) short Hb[4][16][72];     // per-wave H[px][h] bf16 (72 = 64 + pad)

    const int tid = threadIdx.x;
    const int wv  = tid >> 6;
    const int l   = tid & 63;
    const int px  = l & 15;
    const int g   = l >> 4;

    const int b  = blockIdx.z;
    const int x0 = blockIdx.x * TX;
    const int y0 = blockIdx.y * TY;

    // ---- stage state tile (halo, zero "SAME" pad) ----
    const float* sb = sin + b * CHIMG;
    for (int idx = tid; idx < NCH*6*18; idx += 256) {
        int c  = idx / 108;
        int r  = idx - c*108;
        int yy = r / 18;
        int xx = r - yy*18;
        int gy = y0 + yy - 1;
        int gx = x0 + xx - 1;
        float v = 0.f;
        if ((unsigned)gy < (unsigned)HW && (unsigned)gx < (unsigned)HW)
            v = sb[c*IMG + gy*HW + gx];
        ((float*)st)[idx] = v;
    }
    // ---- pack w1 (+b1 in t=3 slot of channel 0) into A-fragment layout ----
    for (int idx = tid; idx < 12*64*8; idx += 256) {
        int j  = idx & 7;
        int ll = (idx >> 3) & 63;
        int fs = idx >> 9;            // 0..11 = m*3+s
        int m  = fs / 3, s = fs - 3*m;
        int row = m*16 + (ll & 15);   // h
        int kp  = 32*s + 8*(ll >> 4) + j;   // k' = 4c+t
        int c = kp >> 2, t = kp & 3;
        float v;
        if (t < 3) v = w1[row*72 + 3*c + t];
        else       v = (c == 0) ? b1[row] : 0.f;
        w1f[idx] = (short)__builtin_bit_cast(unsigned short, (__bf16)v);
    }
    // ---- pack w2 (rows >=24 zero) ----
    for (int idx = tid; idx < 4*64*8; idx += 256) {
        int j  = idx & 7;
        int ll = (idx >> 3) & 63;
        int fs = idx >> 9;            // 0..3 = m2*2+s2
        int m2 = fs >> 1, s2 = fs & 1;
        int row = m2*16 + (ll & 15);  // o
        int h   = 32*s2 + 8*(ll >> 4) + j;
        float v = (row < 24) ? w2[row*64 + h] : 0.f;
        w2f[idx] = (short)__builtin_bit_cast(unsigned short, (__bf16)v);
    }
    // ---- pack b2 per-lane float4 ----
    for (int idx = tid; idx < 2*64*4; idx += 256) {
        int r  = idx & 3;
        int ll = (idx >> 2) & 63;
        int m2 = idx >> 8;
        int o  = m2*16 + 4*(ll >> 4) + r;
        b2f[idx] = (o < 24) ? b2[o] : 0.f;
    }
    __syncthreads();

    // ---- perception directly into B-fragments ----
    // lane owns pixel px of wave-row wv; K-step s covers channels 8s+2g, 8s+2g+1 (4 slots each)
    const int xc = px + 1;
    const int yc = wv + 1;
    bf16x8 pf[3];
    #pragma unroll
    for (int s = 0; s < 3; ++s) {
        #pragma unroll
        for (int cl = 0; cl < 2; ++cl) {
            int c = 8*s + 2*g + cl;
            const float* bp = &st[c][yc-1][xc-1];
            float v00 = bp[0],  v01 = bp[1],  v02 = bp[2];
            float v10 = bp[18], v11 = bp[19], v12 = bp[20];
            float v20 = bp[36], v21 = bp[37], v22 = bp[38];
            pf[s][4*cl+0] = (__bf16)v11;                                                   // identity
            pf[s][4*cl+1] = (__bf16)((v02 - v00 + 2.f*(v12 - v10) + v22 - v20) * 0.125f);  // sobel-x
            pf[s][4*cl+2] = (__bf16)((v20 - v00 + 2.f*(v21 - v01) + v22 - v02) * 0.125f);  // sobel-y
            pf[s][4*cl+3] = (__bf16)((c == 0) ? 1.f : 0.f);                                // bias slot
        }
    }

    // ---- GEMM1: H^T = w1' x p~^T ----
    f32x4 acc1[4] = {};
    #pragma unroll
    for (int m = 0; m < 4; ++m) {
        #pragma unroll
        for (int s = 0; s < 3; ++s) {
            bf16x8 a = *(const bf16x8*)&w1f[((m*3 + s)*64 + l)*8];
            acc1[m] = __builtin_amdgcn_mfma_f32_16x16x32_bf16(a, pf[s], acc1[m], 0, 0, 0);
        }
    }

    // ---- relu + transpose H through per-wave LDS ----
    #pragma unroll
    for (int m = 0; m < 4; ++m) {
        #pragma unroll
        for (int rp = 0; rp < 2; ++rp) {
            float lo = fmaxf(acc1[m][2*rp+0], 0.f);
            float hi = fmaxf(acc1[m][2*rp+1], 0.f);
            unsigned int blo = __builtin_bit_cast(unsigned short, (__bf16)lo);
            unsigned int bhi = __builtin_bit_cast(unsigned short, (__bf16)hi);
            int h0 = m*16 + 4*g + 2*rp;       // D row = 4*g + r (+16 per m-tile)
            *(unsigned int*)&Hb[wv][px][h0] = blo | (bhi << 16);
        }
    }
    // (same-wave write->read; compiler inserts lgkmcnt wait, no barrier needed)

    // ---- GEMM2: delta^T = w2 x relu(H)^T ----
    f32x4 acc2[2] = {};
    #pragma unroll
    for (int s2 = 0; s2 < 2; ++s2) {
        bf16x8 hv = *(const bf16x8*)&Hb[wv][px][8*g + 32*s2];
        #pragma unroll
        for (int m2 = 0; m2 < 2; ++m2) {
            bf16x8 a2 = *(const bf16x8*)&w2f[((m2*2 + s2)*64 + l)*8];
            acc2[m2] = __builtin_amdgcn_mfma_f32_16x16x32_bf16(a2, hv, acc2[m2], 0, 0, 0);
        }
    }

    // ---- epilogue: fire mask + residual + store ----
    const int x = x0 + px;
    const int y = y0 + wv;
    float mval = mask[b*IMG + y*HW + x];
    float fire = (mval < 0.5f) ? 1.f : 0.f;
    f32x4 b2v0 = *(const f32x4*)&b2f[(0*64 + l)*4];
    f32x4 b2v1 = *(const f32x4*)&b2f[(1*64 + l)*4];
    float* ob = sout + b*CHIMG + y*HW + x;
    #pragma unroll
    for (int r = 0; r < 4; ++r) {
        int o0 = 4*g + r;                       // always < 16
        float res = st[o0][yc][xc] + (acc2[0][r] + b2v0[r]) * fire;
        ob[o0*IMG] = res;
    }
    if (g < 2) {
        #pragma unroll
        for (int r = 0; r < 4; ++r) {
            int o1 = 16 + 4*g + r;              // 16..23
            float res = st[o1][yc][xc] + (acc2[1][r] + b2v1[r]) * fire;
            ob[o1*IMG] = res;
        }
    }
}

extern "C" void kernel_launch(void* const* d_in, const int* in_sizes, int n_in,
                              void* d_out, int out_size, void* d_ws, size_t ws_size,
                              hipStream_t stream) {
    const float* state = (const float*)d_in[0];
    const float* w1    = (const float*)d_in[1];
    const float* b1    = (const float*)d_in[2];
    const float* w2    = (const float*)d_in[3];
    const float* b2    = (const float*)d_in[4];
    const float* masks = (const float*)d_in[5];

    float* out = (float*)d_out;
    float* ws  = (float*)d_ws;

    dim3 grid(HW / TX, HW / TY, 4);   // 8 x 32 x 4 = 1024 blocks
    dim3 block(256, 1, 1);

    for (int step = 0; step < 32; ++step) {
        const float* src = (step == 0) ? state : ((step % 2 == 1) ? ws : out);
        float*       dst = (step % 2 == 0) ? ws : out;
        const float* mstep = masks + (size_t)step * 4 * IMG;
        nca_step_mfma<<<grid, block, 0, stream>>>(src, dst, w1, b1, w2, b2, mstep);
    }
}

// Round 4
// 277.778 us; speedup vs baseline: 4.8188x; 1.8704x over previous
//
#include <hip/hip_runtime.h>

typedef __bf16 bf16x8 __attribute__((ext_vector_type(8)));
typedef float  f32x4  __attribute__((ext_vector_type(4)));

#define NCH 24
#define HW 128
#define IMG (HW*HW)
#define CHIMG (NCH*IMG)

// d_ws layout: [state ping buffer: 4*CHIMG floats][packed w1 frags][w2 frags][b2 frags]
#define PW1_OFF ((size_t)(4*CHIMG)*4)          // bytes; 16B-aligned
#define PW2_OFF (PW1_OFF + 12*64*8*2)
#define PB2_OFF (PW2_OFF + 4*64*8*2)

// One-time weight packing into MFMA A-fragment layout (bias-1 trick in t=3 slot).
// mfma_f32_16x16x32_bf16: A[row=l%16][k=8*(l/16)+j], B[k][col=l%16], D[row=4*(l/16)+r][col=l%16]
__global__ void nca_pack_weights(const float* __restrict__ w1, const float* __restrict__ b1,
                                 const float* __restrict__ w2, const float* __restrict__ b2,
                                 char* __restrict__ ws)
{
    short* pw1 = (short*)(ws + PW1_OFF);
    short* pw2 = (short*)(ws + PW2_OFF);
    float* pb2 = (float*)(ws + PB2_OFF);
    const int tid = threadIdx.x;
    for (int idx = tid; idx < 12*64*8; idx += 256) {
        int j  = idx & 7;
        int ll = (idx >> 3) & 63;
        int fs = idx >> 9;                  // m*3+s
        int m  = fs / 3, s = fs - 3*m;
        int row = m*16 + (ll & 15);         // h
        int kp  = 32*s + 8*(ll >> 4) + j;   // k' = 4c+t
        int c = kp >> 2, tt = kp & 3;
        float v;
        if (tt < 3) v = w1[row*72 + 3*c + tt];
        else        v = (c == 0) ? b1[row] : 0.f;
        pw1[idx] = (short)__builtin_bit_cast(unsigned short, (__bf16)v);
    }
    for (int idx = tid; idx < 4*64*8; idx += 256) {
        int j  = idx & 7;
        int ll = (idx >> 3) & 63;
        int fs = idx >> 9;                  // m2*2+s2
        int m2 = fs >> 1, s2 = fs & 1;
        int row = m2*16 + (ll & 15);        // o
        int h   = 32*s2 + 8*(ll >> 4) + j;
        float v = (row < 24) ? w2[row*64 + h] : 0.f;
        pw2[idx] = (short)__builtin_bit_cast(unsigned short, (__bf16)v);
    }
    for (int idx = tid; idx < 2*64*4; idx += 256) {
        int r  = idx & 3;
        int ll = (idx >> 2) & 63;
        int m2 = idx >> 8;
        int o  = m2*16 + 4*(ll >> 4) + r;
        pb2[idx] = (o < 24) ? b2[o] : 0.f;
    }
}

__global__ __launch_bounds__(256, 4) void nca_step(
    const float* __restrict__ sin, float* __restrict__ sout,
    const char* __restrict__ wsp, const float* __restrict__ mask)
{
    __shared__ float st[NCH][6][18];     // state tile + halo (10368 B)
    __shared__ short Hb[4][16][72];      // per-wave H transpose buffer (9216 B)

    const short* __restrict__ pw1 = (const short*)(wsp + PW1_OFF);
    const short* __restrict__ pw2 = (const short*)(wsp + PW2_OFF);
    const float* __restrict__ pb2 = (const float*)(wsp + PB2_OFF);

    const int tid = threadIdx.x;
    const int wv  = tid >> 6;
    const int l   = tid & 63;
    const int px  = l & 15;
    const int g   = l >> 4;

    // XCD-contiguous tile mapping: XCD k (bid%8) owns tiles [128k, 128k+128)
    // = a contiguous half-batch slab -> ping-pong state stays in that XCD's L2.
    const int bid = blockIdx.x;
    const int t   = (bid & 7) * 128 + (bid >> 3);
    const int b   = t >> 8;
    const int y0  = ((t >> 3) & 31) * 4;
    const int x0  = (t & 7) * 16;

    // ---- stage state tile (zero "SAME" pad) ----
    const float* sb = sin + b * CHIMG;
    for (int idx = tid; idx < NCH*6*18; idx += 256) {
        int c  = idx / 108;
        int r  = idx - c*108;
        int yy = r / 18;
        int xx = r - yy*18;
        int gy = y0 + yy - 1;
        int gx = x0 + xx - 1;
        float v = 0.f;
        if ((unsigned)gy < (unsigned)HW && (unsigned)gx < (unsigned)HW)
            v = sb[c*IMG + gy*HW + gx];
        ((float*)st)[idx] = v;
    }
    __syncthreads();

    // ---- perception directly into B-fragments ----
    const int xc = px + 1;
    const int yc = wv + 1;
    bf16x8 pf[3];
    #pragma unroll
    for (int s = 0; s < 3; ++s) {
        #pragma unroll
        for (int cl = 0; cl < 2; ++cl) {
            int c = 8*s + 2*g + cl;
            const float* bp = &st[c][yc-1][xc-1];
            float v00 = bp[0],  v01 = bp[1],  v02 = bp[2];
            float v10 = bp[18], v11 = bp[19], v12 = bp[20];
            float v20 = bp[36], v21 = bp[37], v22 = bp[38];
            pf[s][4*cl+0] = (__bf16)v11;
            pf[s][4*cl+1] = (__bf16)((v02 - v00 + 2.f*(v12 - v10) + v22 - v20) * 0.125f);
            pf[s][4*cl+2] = (__bf16)((v20 - v00 + 2.f*(v21 - v01) + v22 - v02) * 0.125f);
            pf[s][4*cl+3] = (__bf16)((c == 0) ? 1.f : 0.f);
        }
    }

    // ---- GEMM1: H^T = w1' x p~^T (A-frags streamed from L2) ----
    f32x4 acc1[4] = {};
    #pragma unroll
    for (int m = 0; m < 4; ++m) {
        #pragma unroll
        for (int s = 0; s < 3; ++s) {
            bf16x8 a = *(const bf16x8*)&pw1[((m*3 + s)*64 + l)*8];
            acc1[m] = __builtin_amdgcn_mfma_f32_16x16x32_bf16(a, pf[s], acc1[m], 0, 0, 0);
        }
    }

    // ---- relu + per-wave transpose (same-wave LDS, no barrier needed) ----
    #pragma unroll
    for (int m = 0; m < 4; ++m) {
        #pragma unroll
        for (int rp = 0; rp < 2; ++rp) {
            float lo = fmaxf(acc1[m][2*rp+0], 0.f);
            float hi = fmaxf(acc1[m][2*rp+1], 0.f);
            unsigned int blo = __builtin_bit_cast(unsigned short, (__bf16)lo);
            unsigned int bhi = __builtin_bit_cast(unsigned short, (__bf16)hi);
            int h0 = m*16 + 4*g + 2*rp;
            *(unsigned int*)&Hb[wv][px][h0] = blo | (bhi << 16);
        }
    }

    // ---- GEMM2: delta^T = w2 x relu(H)^T ----
    f32x4 acc2[2] = {};
    #pragma unroll
    for (int s2 = 0; s2 < 2; ++s2) {
        bf16x8 hv = *(const bf16x8*)&Hb[wv][px][8*g + 32*s2];
        #pragma unroll
        for (int m2 = 0; m2 < 2; ++m2) {
            bf16x8 a2 = *(const bf16x8*)&pw2[((m2*2 + s2)*64 + l)*8];
            acc2[m2] = __builtin_amdgcn_mfma_f32_16x16x32_bf16(a2, hv, acc2[m2], 0, 0, 0);
        }
    }

    // ---- epilogue: fire mask + residual + store ----
    const int x = x0 + px;
    const int y = y0 + wv;
    float mval = mask[b*IMG + y*HW + x];
    float fire = (mval < 0.5f) ? 1.f : 0.f;
    f32x4 b2v0 = *(const f32x4*)&pb2[(0*64 + l)*4];
    f32x4 b2v1 = *(const f32x4*)&pb2[(1*64 + l)*4];
    float* ob = sout + b*CHIMG + y*HW + x;
    #pragma unroll
    for (int r = 0; r < 4; ++r) {
        int o0 = 4*g + r;                   // 0..15
        ob[o0*IMG] = st[o0][yc][xc] + (acc2[0][r] + b2v0[r]) * fire;
    }
    if (g < 2) {
        #pragma unroll
        for (int r = 0; r < 4; ++r) {
            int o1 = 16 + 4*g + r;          // 16..23
            ob[o1*IMG] = st[o1][yc][xc] + (acc2[1][r] + b2v1[r]) * fire;
        }
    }
}

extern "C" void kernel_launch(void* const* d_in, const int* in_sizes, int n_in,
                              void* d_out, int out_size, void* d_ws, size_t ws_size,
                              hipStream_t stream) {
    const float* state = (const float*)d_in[0];
    const float* w1    = (const float*)d_in[1];
    const float* b1    = (const float*)d_in[2];
    const float* w2    = (const float*)d_in[3];
    const float* b2    = (const float*)d_in[4];
    const float* masks = (const float*)d_in[5];

    float* out = (float*)d_out;   // odd steps write here; step 31 -> out
    float* ws  = (float*)d_ws;    // even steps write state here; weights packed past state

    nca_pack_weights<<<dim3(1), dim3(256), 0, stream>>>(w1, b1, w2, b2, (char*)d_ws);

    for (int step = 0; step < 32; ++step) {
        const float* src = (step == 0) ? state : ((step % 2 == 1) ? ws : out);
        float*       dst = (step % 2 == 0) ? ws : out;
        const float* mstep = masks + (size_t)step * 4 * IMG;
        nca_step<<<dim3(1024), dim3(256), 0, stream>>>(src, dst, (const char*)d_ws, mstep);
    }
}